// Round 7
// baseline (283.611 us; speedup 1.0000x reference)
//
#include <hip/hip_runtime.h>
#include <cstdint>
#include <math.h>

typedef unsigned short u16;
typedef __attribute__((ext_vector_type(8))) short short8;
typedef __attribute__((ext_vector_type(16))) float f32x16;

// RNE float -> bf16 (bit pattern)
__device__ __forceinline__ u16 f2bf(float f) {
  uint32_t u = __float_as_uint(f);
  u += 0x7FFFu + ((u >> 16) & 1u);
  return (u16)(u >> 16);
}
__device__ __forceinline__ float bf2f(u16 h) {
  return __uint_as_float(((uint32_t)h) << 16);
}

// async global->LDS, 16B per lane. LDS dest must be wave-uniform base + lane*16.
__device__ __forceinline__ void async_ld16(u16* lds, const u16* g) {
  __builtin_amdgcn_global_load_lds((const __attribute__((address_space(1))) uint32_t*)g,
                                   (__attribute__((address_space(3))) uint32_t*)lds,
                                   16, 0, 0);
}

// ---------------------------------------------------------------------------
// C[M,N] = A[M,K] * B[N,K]^T (both K-major bf16), 128x128 tile, BK=32,
// double-buffered (1 barrier/iter, prefetch after barrier). 4 waves, each a
// 64x64 quadrant = 2x2 frags of 32x32x16. XOR LDS swizzle (r5).
// r7: attention GEMMs back to this 128^2 core (r6's 64x128 tiles cost 1.5x
// LDS bytes/FLOP — LDS pipe is the floor at ~578cyc/block-iter, not TLP).
// MODE (XCD round-robin = flat_id & 7, verified r2):
//   1: QKV swizzle — XCD u gets mb in [8u,8u+8), all 8 nb (grid 512)
//   2: causal scores triangular, XCD u owns rows {u,15-u} (grid 136)
//   3: causal PV, XCD u owns mb {u,15-u}, 8 nb (grid 128)
// KLIM: clip k-loop at (mb+1)*128 (causal PV).
// EPI: 1 = bf16 out * scale (QKV)
//      2 = scores: exp(acc*scale), causal mask, bf16 out, fused fp32 rowsum
//          via shfl_xor reduce + one atomicAdd per row-half into l
//      3 = PV: fp32 out, divided by l[row]
// ---------------------------------------------------------------------------
template <int MODE, bool KLIM, int EPI>
__global__ __launch_bounds__(256) void gemm_bt(
    const u16* __restrict__ A, int lda, long zsA,
    const u16* __restrict__ B, int ldb, long zsB,
    void* __restrict__ Cv, int ldc, long zsC,
    float* __restrict__ l, int K, float scale, int NB)
{
  const int b = blockIdx.x, zb = blockIdx.y;
  int nb, mb;
  if constexpr (MODE == 1) {
    const int u = b & 7, v = b >> 3;
    nb = v & (NB - 1);
    mb = u * ((int)(gridDim.x >> 3) / NB) + (v / NB);
  } else if constexpr (MODE == 2) {
    const int u = b & 7, idx = b >> 3;  // [0,17)
    if (idx <= u) { mb = u;      nb = idx; }
    else          { mb = 15 - u; nb = idx - u - 1; }
  } else if constexpr (MODE == 3) {
    const int u = b & 7, idx = b >> 3;  // [0,16)
    mb = (idx < 8) ? u : 15 - u;
    nb = idx & 7;
  } else {
    nb = b % NB;
    mb = b / NB;
  }

  A += (long)zb * zsA;
  B += (long)zb * zsB;
  const int m0 = mb * 128, n0 = nb * 128;

  __shared__ __align__(16) u16 lsA[2][128 * 32];
  __shared__ __align__(16) u16 lsB[2][128 * 32];

  const int tid = threadIdx.x;
  const int lane = tid & 63;
  const int wave = tid >> 6;
  const int wr = (wave >> 1) * 64;
  const int wc = (wave & 1) * 64;

  f32x16 acc[2][2];
#pragma unroll
  for (int i = 0; i < 2; ++i)
#pragma unroll
    for (int j = 0; j < 2; ++j)
#pragma unroll
      for (int r = 0; r < 16; ++r) acc[i][j][r] = 0.f;

  const int c0 = tid;
  const int c1 = tid + 256;
  const int r0 = c0 >> 2, q0 = ((c0 & 3) ^ ((c0 >> 3) & 3)) * 8;
  const int r1 = c1 >> 2, q1 = ((c1 & 3) ^ ((c1 >> 3) & 3)) * 8;

  const int klim = (mb + 1) * 128;
  const int kmax = KLIM ? (K < klim ? K : klim) : K;

  const u16* pA0 = A + (long)(m0 + r0) * lda + q0;
  const u16* pA1 = A + (long)(m0 + r1) * lda + q1;
  const u16* pB0 = B + (long)(n0 + r0) * ldb + q0;
  const u16* pB1 = B + (long)(n0 + r1) * ldb + q1;

  const int m32 = lane & 31;
  const int hh = lane >> 5;
  const int rsw = (m32 >> 1) & 3;
  int offA[2][2], offB[2][2];
#pragma unroll
  for (int i = 0; i < 2; ++i)
#pragma unroll
    for (int ks = 0; ks < 2; ++ks) {
      const int kq = ((ks << 1) | hh) ^ rsw;
      offA[i][ks] = (wr + i * 32 + m32) * 32 + kq * 8;
      offB[i][ks] = (wc + i * 32 + m32) * 32 + kq * 8;
    }

  async_ld16(&lsA[0][c0 * 8], pA0);
  async_ld16(&lsA[0][c1 * 8], pA1);
  async_ld16(&lsB[0][c0 * 8], pB0);
  async_ld16(&lsB[0][c1 * 8], pB1);
  pA0 += 32; pA1 += 32; pB0 += 32; pB1 += 32;

  int p = 0;
  for (int k0 = 0; k0 < kmax; k0 += 32) {
    __syncthreads();
    if (k0 + 32 < kmax) {
      async_ld16(&lsA[p ^ 1][c0 * 8], pA0);
      async_ld16(&lsA[p ^ 1][c1 * 8], pA1);
      async_ld16(&lsB[p ^ 1][c0 * 8], pB0);
      async_ld16(&lsB[p ^ 1][c1 * 8], pB1);
      pA0 += 32; pA1 += 32; pB0 += 32; pB1 += 32;
    }

    const u16* la = lsA[p];
    const u16* lb = lsB[p];
#pragma unroll
    for (int ks = 0; ks < 2; ++ks) {
      const short8 a0 = *(const short8*)&la[offA[0][ks]];
      const short8 a1 = *(const short8*)&la[offA[1][ks]];
      const short8 b0 = *(const short8*)&lb[offB[0][ks]];
      const short8 b1 = *(const short8*)&lb[offB[1][ks]];
      acc[0][0] = __builtin_amdgcn_mfma_f32_32x32x16_bf16(a0, b0, acc[0][0], 0, 0, 0);
      acc[0][1] = __builtin_amdgcn_mfma_f32_32x32x16_bf16(a0, b1, acc[0][1], 0, 0, 0);
      acc[1][0] = __builtin_amdgcn_mfma_f32_32x32x16_bf16(a1, b0, acc[1][0], 0, 0, 0);
      acc[1][1] = __builtin_amdgcn_mfma_f32_32x32x16_bf16(a1, b1, acc[1][1], 0, 0, 0);
    }
    p ^= 1;
  }

  // C/D layout 32x32 (m74/m101): col = lane&31, row = (reg&3)+8*(reg>>2)+4*(lane>>5)
  const int ec = lane & 31;
  const int rb = (lane >> 5) * 4;

  if constexpr (EPI == 1) {
    u16* C = (u16*)Cv + (long)zb * zsC;
#pragma unroll
    for (int i = 0; i < 2; ++i) {
      const int rbase = m0 + wr + i * 32 + rb;
#pragma unroll
      for (int j = 0; j < 2; ++j) {
        const int col = n0 + wc + j * 32 + ec;
#pragma unroll
        for (int r = 0; r < 16; ++r) {
          const int row = rbase + (r & 3) + 8 * (r >> 2);
          C[(long)row * ldc + col] = f2bf(acc[i][j][r] * scale);
        }
      }
    }
  } else if constexpr (EPI == 2) {
    u16* C = (u16*)Cv + (long)zb * zsC;
    float* lz = l + (long)zb * 2048;
#pragma unroll
    for (int i = 0; i < 2; ++i) {
      const int rbase = m0 + wr + i * 32 + rb;
      float rsum[16];
#pragma unroll
      for (int r = 0; r < 16; ++r) rsum[r] = 0.f;
#pragma unroll
      for (int j = 0; j < 2; ++j) {
        const int col = n0 + wc + j * 32 + ec;
#pragma unroll
        for (int r = 0; r < 16; ++r) {
          const int row = rbase + (r & 3) + 8 * (r >> 2);
          float pv = __expf(acc[i][j][r] * scale);
          if (col > row) pv = 0.f;
          C[(long)row * ldc + col] = f2bf(pv);
          rsum[r] += pv;
        }
      }
      // reduce each row partial over the 32 col-lanes of this half-wave
#pragma unroll
      for (int r = 0; r < 16; ++r) {
        float s = rsum[r];
#pragma unroll
        for (int off = 1; off < 32; off <<= 1) s += __shfl_xor(s, off, 64);
        if ((lane & 31) == 0)
          atomicAdd(&lz[rbase + (r & 3) + 8 * (r >> 2)], s);
      }
    }
  } else {
    float* C = (float*)Cv + (long)zb * zsC;
    const float* lz = l + (long)zb * 2048;
#pragma unroll
    for (int i = 0; i < 2; ++i) {
      const int rbase = m0 + wr + i * 32 + rb;
#pragma unroll
      for (int j = 0; j < 2; ++j) {
        const int col = n0 + wc + j * 32 + ec;
#pragma unroll
        for (int r = 0; r < 16; ++r) {
          const int row = rbase + (r & 3) + 8 * (r >> 2);
          C[(long)row * ldc + col] = acc[i][j][r] / lz[row];
        }
      }
    }
  }
}

// ---------------------------------------------------------------------------
// X fp32 -> bf16; block 0 also zeroes l (8192 floats) for the fused rowsum.
// ---------------------------------------------------------------------------
__global__ __launch_bounds__(256) void cast_x_kernel(const float* __restrict__ x,
                                                     u16* __restrict__ y,
                                                     float* __restrict__ l) {
  const long i = ((long)blockIdx.x * 256 + threadIdx.x) * 4;
  const float4 v = *(const float4*)(x + i);
  ushort4 o;
  o.x = f2bf(v.x); o.y = f2bf(v.y); o.z = f2bf(v.z); o.w = f2bf(v.w);
  *(ushort4*)(y + i) = o;
  if (blockIdx.x == 0) {
    float4 z = {0.f, 0.f, 0.f, 0.f};
#pragma unroll
    for (int k = 0; k < 8; ++k)
      ((float4*)l)[threadIdx.x * 8 + k] = z;
  }
}

// ---------------------------------------------------------------------------
// W[k][n] fp32 -> Wt[n][k] bf16
// ---------------------------------------------------------------------------
__global__ __launch_bounds__(256) void cast_wt_kernel(const float* __restrict__ w0,
                                                      const float* __restrict__ w1,
                                                      const float* __restrict__ w2,
                                                      u16* __restrict__ Wt) {
  const float* W = (blockIdx.z == 0) ? w0 : (blockIdx.z == 1) ? w1 : w2;
  u16* o = Wt + (long)blockIdx.z * 1024 * 1024;
  __shared__ float t[32][33];
  const int n0 = blockIdx.x * 32, k0 = blockIdx.y * 32;
  const int tx = threadIdx.x, ty = threadIdx.y;
  for (int r = ty; r < 32; r += 8) t[r][tx] = W[(long)(k0 + r) * 1024 + n0 + tx];
  __syncthreads();
  for (int r = ty; r < 32; r += 8) o[(long)(n0 + r) * 1024 + k0 + tx] = f2bf(t[tx][r]);
}

// ---------------------------------------------------------------------------
// V[b][t][d] bf16 -> Vt[b][d][t] bf16
// ---------------------------------------------------------------------------
__global__ __launch_bounds__(256) void transpose_v_kernel(const u16* __restrict__ V,
                                                          u16* __restrict__ Vt) {
  __shared__ u16 t[32][33];
  const int d0 = blockIdx.x * 32, t0 = blockIdx.y * 32, b = blockIdx.z;
  const u16* Vb = V + (long)b * 2048 * 1024;
  u16* Ob = Vt + (long)b * 1024 * 2048;
  const int tx = threadIdx.x, ty = threadIdx.y;
  for (int r = ty; r < 32; r += 8) t[r][tx] = Vb[(long)(t0 + r) * 1024 + d0 + tx];
  __syncthreads();
  for (int r = ty; r < 32; r += 8) Ob[(long)(d0 + r) * 2048 + t0 + tx] = t[tx][r];
}

// ---------------------------------------------------------------------------
extern "C" void kernel_launch(void* const* d_in, const int* in_sizes, int n_in,
                              void* d_out, int out_size, void* d_ws, size_t ws_size,
                              hipStream_t stream) {
  const float* X  = (const float*)d_in[0];
  const float* Wq = (const float*)d_in[1];
  const float* Wk = (const float*)d_in[2];
  const float* Wv = (const float*)d_in[3];
  float* out = (float*)d_out;

  const long BT = 8192;
  const long Tq = 2048, D = 1024;

  // workspace (~118 MiB)
  u16* Xbf = (u16*)d_ws;                // 16 MB
  u16* Wt  = Xbf + BT * D;              //  6 MB
  u16* QKV = Wt + 3 * D * D;            // 48 MB
  u16* Vt  = QKV + 3 * BT * D;          // 16 MB
  u16* P   = Vt + 4 * D * Tq;           // 32 MB (exp(S), unnormalized)
  float* l = (float*)(P + 4 * Tq * Tq); // 32 KB row sums

  cast_x_kernel<<<8192, 256, 0, stream>>>(X, Xbf, l);
  cast_wt_kernel<<<dim3(32, 32, 3), dim3(32, 8), 0, stream>>>(Wq, Wk, Wv, Wt);

  // QKV: MODE 1 XCD swizzle, bf16 epilogue
  gemm_bt<1, false, 1><<<dim3(512, 3), 256, 0, stream>>>(
      Xbf, 1024, 0L, Wt, 1024, D * D, QKV, 1024, BT * D, nullptr, 1024, 1.0f, 8);

  // scores: exp(Q*K^T/32), causal mask, bf16 P + fused fp32 rowsum -> l
  gemm_bt<2, false, 2><<<dim3(136, 4), 256, 0, stream>>>(
      QKV, 1024, Tq * D, QKV + BT * D, 1024, Tq * D,
      P, 2048, Tq * Tq, l, 1024, 0.03125f, 16);

  // V -> Vt
  transpose_v_kernel<<<dim3(32, 64, 4), dim3(32, 8), 0, stream>>>(QKV + 2 * BT * D, Vt);

  // PV: k clipped at diagonal, epilogue / l[row]
  gemm_bt<3, true, 3><<<dim3(128, 4), 256, 0, stream>>>(
      P, 2048, Tq * Tq, Vt, 2048, D * Tq,
      out, 1024, Tq * D, l, 2048, 1.0f, 8);
}

// Round 8
// 253.004 us; speedup vs baseline: 1.1210x; 1.1210x over previous
//
#include <hip/hip_runtime.h>
#include <cstdint>

typedef unsigned short u16;
typedef __attribute__((ext_vector_type(8))) short short8;
typedef __attribute__((ext_vector_type(16))) float f32x16;

// RNE float -> bf16 (bit pattern)
__device__ __forceinline__ u16 f2bf(float f) {
  uint32_t u = __float_as_uint(f);
  u += 0x7FFFu + ((u >> 16) & 1u);
  return (u16)(u >> 16);
}

// async global->LDS, 16B per lane. LDS dest must be wave-uniform base + lane*16.
__device__ __forceinline__ void async_ld16(u16* lds, const u16* g) {
  __builtin_amdgcn_global_load_lds((const __attribute__((address_space(1))) uint32_t*)g,
                                   (__attribute__((address_space(3))) uint32_t*)lds,
                                   16, 0, 0);
}

// ---------------------------------------------------------------------------
// Unified 128x128xBK32 double-buffered C = A*B^T core (both operands K-major
// bf16), 4 waves of 2x2 32x32x16 frags, XOR LDS swizzle, 1 barrier/iter.
// ROLE 0: QK projections. grid 1024. XCD u: X-row-tiles [8u,8u+8), mats Q,K.
// ROLE 1: merged dispatch, grid 1056 (r8: fills TLP — scores alone was 2.1
//         blocks/CU, ~2.6x ideal):
//         b<544  : causal scores, exp + causal mask -> P bf16, per-chunk
//                  fp32 row-partials -> lpart (plain stores, no atomics;
//                  r7's atomicAdd rowsum cost ~24us).
//         b>=544 : V^T projection DIRECTLY: Vt = Wtv * Xbf^T via operand
//                  swap (A=Wtv rows d, B=Xbf rows t) -> no transpose kernel.
// ROLE 2: PV, grid (128,4), big-mb-first, K clipped at diagonal; epilogue
//         builds 1/l per row from lpart chunks, multiplies, fp32 out.
// ---------------------------------------------------------------------------
template <int ROLE>
__global__ __launch_bounds__(256) void gk(
    const u16* __restrict__ Xbf, const u16* __restrict__ Wt,
    u16* __restrict__ QK, u16* __restrict__ VtAll,
    u16* __restrict__ P, float* __restrict__ lpart,
    float* __restrict__ out)
{
  const int b = blockIdx.x;
  const int tid = threadIdx.x;
  const int lane = tid & 63;
  const int wave = tid >> 6;
  const int wr = (wave >> 1) * 64;
  const int wc = (wave & 1) * 64;

  __shared__ __align__(16) u16 ls[4][4096];  // A0,A1,B0,B1 (128x32 each)
  __shared__ float l_s[128];                 // ROLE 2 only

  // staging slots: granule c -> row c>>2, source k-granule (c&3)^((c>>3)&3)
  const int c0 = tid, c1 = tid + 256;
  const int r0 = c0 >> 2, q0 = ((c0 & 3) ^ ((c0 >> 3) & 3)) * 8;
  const int r1 = c1 >> 2, q1 = ((c1 & 3) ^ ((c1 >> 3) & 3)) * 8;

  // loop-invariant ds_read offsets
  const int m32 = lane & 31;
  const int hh = lane >> 5;
  const int rsw = (m32 >> 1) & 3;
  int offA[2][2], offB[2][2];
#pragma unroll
  for (int i = 0; i < 2; ++i)
#pragma unroll
    for (int ks = 0; ks < 2; ++ks) {
      const int kq = ((ks << 1) | hh) ^ rsw;
      offA[i][ks] = (wr + i * 32 + m32) * 32 + kq * 8;
      offB[i][ks] = (wc + i * 32 + m32) * 32 + kq * 8;
    }

  // ---- per-role operand decode ----
  const u16 *A, *B;
  int lda, ldb, kmax, m0, n0, mb, nb, zb = 0, mat = 0;
  bool scoresRole = false;

  if constexpr (ROLE == 0) {
    const int u = b & 7, v = b >> 3;      // v in [0,128)
    mat = v >> 6;                          // 0=Q, 1=K
    const int w = v & 63;
    nb = w & 7;
    mb = u * 8 + (w >> 3);
    A = Xbf; lda = 1024;
    B = Wt + (long)mat * 1024 * 1024; ldb = 1024;
    kmax = 1024;
  } else if constexpr (ROLE == 1) {
    if (b < 544) {
      scoresRole = true;
      const int u = b & 7, t = b >> 3;    // t in [0,68)
      zb = t / 17;
      const int idx = t % 17;
      if (idx <= u) { mb = u;      nb = idx; }
      else          { mb = 15 - u; nb = idx - u - 1; }
      A = QK + (long)zb * 2048 * 1024; lda = 1024;                    // Q
      B = QK + 8192L * 1024 + (long)zb * 2048 * 1024; ldb = 1024;     // K
      kmax = 1024;
    } else {
      const int v = b - 544;
      const int u = v & 7, w = v >> 3;    // w in [0,64)
      mb = w & 7;                          // d-tile (8)
      nb = u * 8 + (w >> 3);               // t-tile (64), XCD-local X rows
      A = Wt + 2L * 1024 * 1024; lda = 1024;  // Wtv rows d, K-major
      B = Xbf; ldb = 1024;                     // X rows t, K-major
      kmax = 1024;
    }
  } else {  // ROLE 2: PV
    const int u = b & 7, idx = b >> 3;    // idx in [0,16)
    zb = blockIdx.y;
    if (idx < 8) { mb = 15 - u; nb = idx; }      // big work first
    else         { mb = u;      nb = idx - 8; }
    A = P + (long)zb * 2048 * 2048; lda = 2048;
    B = VtAll + (long)zb * 2048; ldb = 8192;     // Vt rows d, batch k-slice
    kmax = (mb + 1) * 128;
  }
  m0 = mb * 128;
  n0 = nb * 128;

  const u16* pA0 = A + (long)(m0 + r0) * lda + q0;
  const u16* pA1 = A + (long)(m0 + r1) * lda + q1;
  const u16* pB0 = B + (long)(n0 + r0) * ldb + q0;
  const u16* pB1 = B + (long)(n0 + r1) * ldb + q1;

  f32x16 acc[2][2];
#pragma unroll
  for (int i = 0; i < 2; ++i)
#pragma unroll
    for (int j = 0; j < 2; ++j)
#pragma unroll
      for (int r = 0; r < 16; ++r) acc[i][j][r] = 0.f;

  // ---- double-buffered K-loop ----
  async_ld16(&ls[0][c0 * 8 - 0], pA0);
  async_ld16(&ls[0][c1 * 8 - 2048 * 0], pA1);  // c1*8 in [2048*? ) -- see note
  // NOTE: ls[0] holds granules c in [0,512) is 4096 u16; c0*8 in [0,2048),
  // c1*8 in [2048,4096). Both land in ls[0]..ls[1]? No: slots c0,c1 both
  // belong to ONE 128x32 tile (4096 u16). c1*8 in [2048,4096) fits ls[0]? 
  // ls[0] is 4096 u16 => yes, both fit in ls[0]. A-bufs: ls[0] (p=0), ls[1]
  // (p=1); B-bufs: ls[2], ls[3].
  async_ld16(&ls[2][c0 * 8], pB0);
  async_ld16(&ls[2][c1 * 8 - 2048 * 0], pB1);
  pA0 += 32; pA1 += 32; pB0 += 32; pB1 += 32;

  int p = 0;
  for (int k0 = 0; k0 < kmax; k0 += 32) {
    __syncthreads();
    if (k0 + 32 < kmax) {
      u16* la = ls[p ^ 1];
      u16* lb = ls[2 + (p ^ 1)];
      async_ld16(&la[c0 * 8], pA0);
      async_ld16(&la[c1 * 8], pA1);
      async_ld16(&lb[c0 * 8], pB0);
      async_ld16(&lb[c1 * 8], pB1);
      pA0 += 32; pA1 += 32; pB0 += 32; pB1 += 32;
    }

    const u16* la = ls[p];
    const u16* lb = ls[2 + p];
#pragma unroll
    for (int ks = 0; ks < 2; ++ks) {
      const short8 a0 = *(const short8*)&la[offA[0][ks]];
      const short8 a1 = *(const short8*)&la[offA[1][ks]];
      const short8 b0 = *(const short8*)&lb[offB[0][ks]];
      const short8 b1 = *(const short8*)&lb[offB[1][ks]];
      acc[0][0] = __builtin_amdgcn_mfma_f32_32x32x16_bf16(a0, b0, acc[0][0], 0, 0, 0);
      acc[0][1] = __builtin_amdgcn_mfma_f32_32x32x16_bf16(a0, b1, acc[0][1], 0, 0, 0);
      acc[1][0] = __builtin_amdgcn_mfma_f32_32x32x16_bf16(a1, b0, acc[1][0], 0, 0, 0);
      acc[1][1] = __builtin_amdgcn_mfma_f32_32x32x16_bf16(a1, b1, acc[1][1], 0, 0, 0);
    }
    p ^= 1;
  }

  // C/D layout 32x32 (m74/m101): col = lane&31, row = (reg&3)+8*(reg>>2)+4*(lane>>5)
  const int ec = lane & 31;
  const int rb = (lane >> 5) * 4;

  if constexpr (ROLE == 0) {
    u16* C = QK + (long)mat * 8192 * 1024;
#pragma unroll
    for (int i = 0; i < 2; ++i) {
      const int rbase = m0 + wr + i * 32 + rb;
#pragma unroll
      for (int j = 0; j < 2; ++j) {
        const int col = n0 + wc + j * 32 + ec;
#pragma unroll
        for (int r = 0; r < 16; ++r) {
          const int row = rbase + (r & 3) + 8 * (r >> 2);
          C[(long)row * 1024 + col] = f2bf(acc[i][j][r]);
        }
      }
    }
  } else if constexpr (ROLE == 1) {
    if (scoresRole) {
      u16* C = P + (long)zb * 2048 * 2048;
      float* lp = lpart + (long)zb * 32 * 2048 + (long)(2 * nb + (wc >> 6)) * 2048;
#pragma unroll
      for (int i = 0; i < 2; ++i) {
        const int rbl = wr + i * 32 + rb;  // local row base [0,128)
        float rsum[16];
#pragma unroll
        for (int r = 0; r < 16; ++r) rsum[r] = 0.f;
#pragma unroll
        for (int j = 0; j < 2; ++j) {
          const int col = n0 + wc + j * 32 + ec;
#pragma unroll
          for (int r = 0; r < 16; ++r) {
            const int row = m0 + rbl + (r & 3) + 8 * (r >> 2);
            float pv = __expf(acc[i][j][r] * 0.03125f);
            if (col > row) pv = 0.f;
            C[(long)row * 2048 + col] = f2bf(pv);
            rsum[r] += pv;
          }
        }
#pragma unroll
        for (int r = 0; r < 16; ++r) {
          float s = rsum[r];
#pragma unroll
          for (int off = 1; off < 32; off <<= 1) s += __shfl_xor(s, off, 64);
          if ((lane & 31) == 0)
            lp[m0 + rbl + (r & 3) + 8 * (r >> 2)] = s;
        }
      }
    } else {
      // Vt[d][t_global]: ldc = 8192
#pragma unroll
      for (int i = 0; i < 2; ++i) {
        const int rbase = m0 + wr + i * 32 + rb;
#pragma unroll
        for (int j = 0; j < 2; ++j) {
          const int col = n0 + wc + j * 32 + ec;
#pragma unroll
          for (int r = 0; r < 16; ++r) {
            const int row = rbase + (r & 3) + 8 * (r >> 2);
            VtAll[(long)row * 8192 + col] = f2bf(acc[i][j][r]);
          }
        }
      }
    }
  } else {
    // PV: build 1/l per row from lpart chunks, then multiply
    __syncthreads();  // staging LDS dead
    if (tid < 128) {
      const float* lp = lpart + (long)zb * 32 * 2048 + m0 + tid;
      float s0 = 0.f, s1 = 0.f;
      const int nch = 2 * (mb + 1);
      for (int c = 0; c < nch; c += 2) {
        s0 += lp[(long)c * 2048];
        s1 += lp[(long)(c + 1) * 2048];
      }
      l_s[tid] = 1.f / (s0 + s1);
    }
    __syncthreads();
    float* C = out + (long)zb * 2048 * 1024;
#pragma unroll
    for (int i = 0; i < 2; ++i) {
      const int rbl = wr + i * 32 + rb;
#pragma unroll
      for (int j = 0; j < 2; ++j) {
        const int col = n0 + wc + j * 32 + ec;
#pragma unroll
        for (int r = 0; r < 16; ++r) {
          const int rl = rbl + (r & 3) + 8 * (r >> 2);
          C[(long)(m0 + rl) * 1024 + col] = acc[i][j][r] * l_s[rl];
        }
      }
    }
  }
}

// ---------------------------------------------------------------------------
// Fused casts: blocks [0,8192): X fp32->bf16 (1024 elems each);
// blocks [8192,11264): W_{q,k,v}[k][n] fp32 -> Wt[n][k] bf16 (32x32 tiles).
// ---------------------------------------------------------------------------
__global__ __launch_bounds__(256) void cast_fused(
    const float* __restrict__ x, const float* __restrict__ w0,
    const float* __restrict__ w1, const float* __restrict__ w2,
    u16* __restrict__ Xbf, u16* __restrict__ Wt)
{
  const int b = blockIdx.x;
  if (b < 8192) {
    const long i = ((long)b * 256 + threadIdx.x) * 4;
    const float4 v = *(const float4*)(x + i);
    ushort4 o;
    o.x = f2bf(v.x); o.y = f2bf(v.y); o.z = f2bf(v.z); o.w = f2bf(v.w);
    *(ushort4*)(Xbf + i) = o;
  } else {
    const int bb = b - 8192;               // [0,3072)
    const int z = bb >> 10, rem = bb & 1023;
    const float* W = (z == 0) ? w0 : (z == 1) ? w1 : w2;
    u16* o = Wt + (long)z * 1024 * 1024;
    __shared__ float t[32][33];
    const int n0 = (rem & 31) * 32, k0 = (rem >> 5) * 32;
    const int tx = threadIdx.x & 31, ty = threadIdx.x >> 5;
    for (int r = ty; r < 32; r += 8) t[r][tx] = W[(long)(k0 + r) * 1024 + n0 + tx];
    __syncthreads();
    for (int r = ty; r < 32; r += 8) o[(long)(n0 + r) * 1024 + k0 + tx] = f2bf(t[tx][r]);
  }
}

// ---------------------------------------------------------------------------
extern "C" void kernel_launch(void* const* d_in, const int* in_sizes, int n_in,
                              void* d_out, int out_size, void* d_ws, size_t ws_size,
                              hipStream_t stream) {
  const float* X  = (const float*)d_in[0];
  const float* Wq = (const float*)d_in[1];
  const float* Wk = (const float*)d_in[2];
  const float* Wv = (const float*)d_in[3];
  float* out = (float*)d_out;

  // workspace (~103 MiB)
  u16* Xbf   = (u16*)d_ws;                   // 8192*1024            16 MB
  u16* Wt    = Xbf + 8192L * 1024;           // 3*1024*1024           6 MB
  u16* QK    = Wt + 3L * 1024 * 1024;        // 2*8192*1024          32 MB
  u16* VtAll = QK + 2L * 8192 * 1024;        // 1024*8192            16 MB
  u16* P     = VtAll + 1024L * 8192;         // 4*2048*2048          32 MB
  float* lpart = (float*)(P + 4L * 2048 * 2048);  // 4*32*2048        1 MB

  cast_fused<<<8192 + 3072, 256, 0, stream>>>(X, Wq, Wk, Wv, Xbf, Wt);

  // Q,K projections (1024 blocks, 4/CU)
  gk<0><<<1024, 256, 0, stream>>>(Xbf, Wt, QK, VtAll, P, lpart, out);

  // merged: causal scores (544) + V^T projection (512) = 1056 blocks
  gk<1><<<1056, 256, 0, stream>>>(Xbf, Wt, QK, VtAll, P, lpart, out);

  // PV: 512 blocks, big-mb-first, epilogue normalizes via lpart
  gk<2><<<dim3(128, 4), 256, 0, stream>>>(Xbf, Wt, QK, VtAll, P, lpart, out);
}